// Round 2
// baseline (147.984 us; speedup 1.0000x reference)
//
#include <hip/hip_runtime.h>

#define N_H 8192
#define RANK 8
#define BATCH 2048
#define RB 4                         // batch rows per block
#define BLOCK 512                    // threads per block (8 waves)
#define CHUNKS_PER_ROW (N_H / 4)     // 2048 float4 per row
#define ITER (CHUNKS_PER_ROW / BLOCK) // 4 chunks per thread per row
#define NWAVES (BLOCK / 64)

__device__ __forceinline__ float fast_tanh(float x) {
    // tanh(x) = 1 - 2/(exp(2x)+1); saturates correctly at +/-inf
    float e = __expf(2.0f * x);
    return 1.0f - 2.0f / (e + 1.0f);
}

__global__ __launch_bounds__(BLOCK) void rnn_fused(
    const float* __restrict__ ff, const float* __restrict__ h,
    const float* __restrict__ U, const float* __restrict__ V,
    float* __restrict__ out)
{
    const int t = threadIdx.x;
    const int b0 = blockIdx.x * RB;
    const float4* __restrict__ H4 = (const float4*)h;
    const float4* __restrict__ V4 = (const float4*)V;   // [RANK][N_H/4]
    const float4* __restrict__ U4 = (const float4*)U;   // [N_H][RANK/4] = [N_H*2]
    const float4* __restrict__ FF4 = (const float4*)ff;
    float4* __restrict__ O4 = (float4*)out;

    // ---- Phase 1: P[b,r] = sum_n tanh(h[b,n]) * V[r,n] (per-thread partials)
    float acc[RB][RANK];
    #pragma unroll
    for (int j = 0; j < RB; ++j)
        #pragma unroll
        for (int r = 0; r < RANK; ++r) acc[j][r] = 0.0f;

    #pragma unroll
    for (int i = 0; i < ITER; ++i) {
        const int c = i * BLOCK + t;              // float4 chunk index in [0, 2048)
        float4 v4[RANK];
        #pragma unroll
        for (int r = 0; r < RANK; ++r) v4[r] = V4[r * CHUNKS_PER_ROW + c];
        #pragma unroll
        for (int j = 0; j < RB; ++j) {
            float4 h4 = H4[(size_t)(b0 + j) * CHUNKS_PER_ROW + c];
            float tx = fast_tanh(h4.x), ty = fast_tanh(h4.y);
            float tz = fast_tanh(h4.z), tw = fast_tanh(h4.w);
            #pragma unroll
            for (int r = 0; r < RANK; ++r)
                acc[j][r] += tx * v4[r].x + ty * v4[r].y + tz * v4[r].z + tw * v4[r].w;
        }
    }

    // ---- Phase 2: block-wide reduction of acc -> P[RB][RANK]
    #pragma unroll
    for (int j = 0; j < RB; ++j)
        #pragma unroll
        for (int r = 0; r < RANK; ++r) {
            float v = acc[j][r];
            #pragma unroll
            for (int off = 32; off >= 1; off >>= 1)
                v += __shfl_xor(v, off, 64);
            acc[j][r] = v;
        }

    __shared__ float red[NWAVES][RB][RANK];
    __shared__ float Pp[RB][RANK];
    const int wave = t >> 6, lane = t & 63;
    if (lane == 0) {
        #pragma unroll
        for (int j = 0; j < RB; ++j)
            #pragma unroll
            for (int r = 0; r < RANK; ++r) red[wave][j][r] = acc[j][r];
    }
    __syncthreads();
    if (t < RB * RANK) {
        const int j = t >> 3, r = t & 7;
        float s = 0.0f;
        #pragma unroll
        for (int w = 0; w < NWAVES; ++w) s += red[w][j][r];
        Pp[j][r] = s;
    }
    __syncthreads();

    float p[RB][RANK];
    #pragma unroll
    for (int j = 0; j < RB; ++j)
        #pragma unroll
        for (int r = 0; r < RANK; ++r) p[j][r] = Pp[j][r];  // LDS broadcast, hoisted

    // ---- Phase 3: out = 0.99*h + 0.01*(ff + (P . U[m,:])/N)
    constexpr float INV_N = 1.0f / (float)N_H;
    constexpr float CA = 1.0f - 0.01f;
    constexpr float CB = 0.01f;

    #pragma unroll
    for (int i = 0; i < ITER; ++i) {
        const int c = i * BLOCK + t;
        float4 f4 = FF4[c];
        float4 u[8];                               // U rows for cols 4c..4c+3
        #pragma unroll
        for (int k = 0; k < 8; ++k) u[k] = U4[(size_t)c * 8 + k];
        #pragma unroll
        for (int j = 0; j < RB; ++j) {
            float4 h4 = H4[(size_t)(b0 + j) * CHUNKS_PER_ROW + c];
            float s0 = p[j][0]*u[0].x + p[j][1]*u[0].y + p[j][2]*u[0].z + p[j][3]*u[0].w
                     + p[j][4]*u[1].x + p[j][5]*u[1].y + p[j][6]*u[1].z + p[j][7]*u[1].w;
            float s1 = p[j][0]*u[2].x + p[j][1]*u[2].y + p[j][2]*u[2].z + p[j][3]*u[2].w
                     + p[j][4]*u[3].x + p[j][5]*u[3].y + p[j][6]*u[3].z + p[j][7]*u[3].w;
            float s2 = p[j][0]*u[4].x + p[j][1]*u[4].y + p[j][2]*u[4].z + p[j][3]*u[4].w
                     + p[j][4]*u[5].x + p[j][5]*u[5].y + p[j][6]*u[5].z + p[j][7]*u[5].w;
            float s3 = p[j][0]*u[6].x + p[j][1]*u[6].y + p[j][2]*u[6].z + p[j][3]*u[6].w
                     + p[j][4]*u[7].x + p[j][5]*u[7].y + p[j][6]*u[7].z + p[j][7]*u[7].w;
            float4 o;
            o.x = CA * h4.x + CB * (f4.x + s0 * INV_N);
            o.y = CA * h4.y + CB * (f4.y + s1 * INV_N);
            o.z = CA * h4.z + CB * (f4.z + s2 * INV_N);
            o.w = CA * h4.w + CB * (f4.w + s3 * INV_N);
            O4[(size_t)(b0 + j) * CHUNKS_PER_ROW + c] = o;
        }
    }
}

extern "C" void kernel_launch(void* const* d_in, const int* in_sizes, int n_in,
                              void* d_out, int out_size, void* d_ws, size_t ws_size,
                              hipStream_t stream) {
    const float* ff = (const float*)d_in[0];   // [8192]
    const float* h  = (const float*)d_in[1];   // [2048, 8192]
    const float* U  = (const float*)d_in[2];   // [8192, 8]
    const float* V  = (const float*)d_in[3];   // [8, 8192]
    float* out = (float*)d_out;                // [2048, 8192]
    rnn_fused<<<dim3(BATCH / RB), dim3(BLOCK), 0, stream>>>(ff, h, U, V, out);
}